// Round 1
// baseline (582.323 us; speedup 1.0000x reference)
//
#include <hip/hip_runtime.h>
#include <hip/hip_bf16.h>

// Problem constants (static graph layout from the reference)
#define NG 128          // graphs
#define NPG 1024        // nodes per graph
#define NN (NG * NPG)   // 131072 nodes
#define NE (NN * 32)    // 4194304 edges
#define CH 256          // channels
#define KSEL 512        // top-k per graph

// Output layout (all float32, concatenated flat in return order)
#define OUT_X      0
#define OUT_EDGE   16777216   // 65536*256
#define OUT_BATCH  25165824   // + 2*4194304
#define OUT_PERM   25231360
#define OUT_SCORES 25296896
// total 25362432 floats

// Workspace layout (bytes)
#define WS_SCORES  0
#define WS_KEEP    524288
#define WS_COUNTS  655360
#define WS_OFFSETS 659456

// ---------------- Kernel 1: scores = tanh(x@W1 + b1) @ W2 + b2 ----------------
// Block: 256 threads, 64 nodes/block. Thread (ng,cg): 4 nodes x 16 cols.
// Columns for thread cg: {jj*64 + cg*4 + j2 : jj in 0..3, j2 in 0..3} -> stride-4
// float4 LDS reads spread across banks (2-way = free).
__global__ __launch_bounds__(256)
void k_scores(const float* __restrict__ x, const float* __restrict__ W1,
              const float* __restrict__ b1, const float* __restrict__ W2,
              const float* __restrict__ b2, float* __restrict__ scores)
{
    __shared__ float Xs[64][260];   // +4 pad: breaks row-stride bank aliasing
    __shared__ float W1s[64][CH];
    const int tid = threadIdx.x;
    const int n0 = blockIdx.x * 64;

    // Stage X tile (64 rows x 256 cols), coalesced float4
    #pragma unroll
    for (int it = 0; it < 16; ++it) {
        int idx = it * 1024 + tid * 4;
        int r = idx >> 8, c = idx & 255;
        *(float4*)&Xs[r][c] = *(const float4*)&x[(size_t)(n0 + r) * CH + c];
    }

    const int cg = tid & 15;
    const int ng = tid >> 4;

    float acc[4][16];
    #pragma unroll
    for (int jj = 0; jj < 4; ++jj) {
        const float4 bb = *(const float4*)&b1[jj * 64 + cg * 4];
        #pragma unroll
        for (int i = 0; i < 4; ++i) {
            acc[i][jj*4+0] = bb.x; acc[i][jj*4+1] = bb.y;
            acc[i][jj*4+2] = bb.z; acc[i][jj*4+3] = bb.w;
        }
    }

    for (int kc = 0; kc < 4; ++kc) {
        __syncthreads();
        #pragma unroll
        for (int it = 0; it < 16; ++it) {
            int idx = it * 1024 + tid * 4;
            int r = idx >> 8, c = idx & 255;
            *(float4*)&W1s[r][c] = *(const float4*)&W1[(size_t)(kc * 64 + r) * CH + c];
        }
        __syncthreads();
        #pragma unroll 8
        for (int k = 0; k < 64; ++k) {
            float xv[4];
            #pragma unroll
            for (int i = 0; i < 4; ++i) xv[i] = Xs[ng * 4 + i][kc * 64 + k];
            #pragma unroll
            for (int jj = 0; jj < 4; ++jj) {
                const float4 w = *(const float4*)&W1s[k][jj * 64 + cg * 4];
                #pragma unroll
                for (int i = 0; i < 4; ++i) {
                    acc[i][jj*4+0] = fmaf(xv[i], w.x, acc[i][jj*4+0]);
                    acc[i][jj*4+1] = fmaf(xv[i], w.y, acc[i][jj*4+1]);
                    acc[i][jj*4+2] = fmaf(xv[i], w.z, acc[i][jj*4+2]);
                    acc[i][jj*4+3] = fmaf(xv[i], w.w, acc[i][jj*4+3]);
                }
            }
        }
    }

    float w2v[16];
    #pragma unroll
    for (int jj = 0; jj < 4; ++jj) {
        const float4 w = *(const float4*)&W2[jj * 64 + cg * 4];
        w2v[jj*4+0] = w.x; w2v[jj*4+1] = w.y; w2v[jj*4+2] = w.z; w2v[jj*4+3] = w.w;
    }
    float part[4] = {0.f, 0.f, 0.f, 0.f};
    #pragma unroll
    for (int i = 0; i < 4; ++i)
        #pragma unroll
        for (int j = 0; j < 16; ++j)
            part[i] += tanhf(acc[i][j]) * w2v[j];

    // reduce across the 16 cg lanes (low 4 bits of lane id)
    #pragma unroll
    for (int off = 1; off < 16; off <<= 1)
        #pragma unroll
        for (int i = 0; i < 4; ++i)
            part[i] += __shfl_xor(part[i], off, 64);

    if (cg == 0) {
        const float bb = b2[0];
        #pragma unroll
        for (int i = 0; i < 4; ++i)
            scores[n0 + ng * 4 + i] = part[i] + bb;
    }
}

// ---------------- Kernel 2: per-graph bitonic top-k (full sort of 1024) -------
__global__ __launch_bounds__(512)
void k_topk(const float* __restrict__ scores, float* __restrict__ out,
            unsigned char* __restrict__ keep)
{
    __shared__ float sv[1024];
    __shared__ int   si[1024];
    const int g = blockIdx.x;
    const int t = threadIdx.x;
    sv[t]       = scores[g * NPG + t];       si[t]       = t;
    sv[t + 512] = scores[g * NPG + t + 512]; si[t + 512] = t + 512;

    for (int size = 2; size <= 1024; size <<= 1) {
        for (int stride = size >> 1; stride > 0; stride >>= 1) {
            __syncthreads();
            const int lo = ((t & ~(stride - 1)) << 1) | (t & (stride - 1));
            const int hi = lo + stride;
            const bool dirDesc = ((lo & size) == 0);
            const float va = sv[lo], vb = sv[hi];
            const int ia = si[lo], ib = si[hi];
            const bool aB = (va > vb) || (va == vb && ia < ib);
            if (aB != dirDesc) {
                sv[lo] = vb; sv[hi] = va;
                si[lo] = ib; si[hi] = ia;
            }
        }
    }
    __syncthreads();
    // rank t of this graph survives (t in [0,512))
    const int gi = g * NPG + si[t];
    out[OUT_PERM   + g * KSEL + t] = (float)gi;
    out[OUT_SCORES + g * KSEL + t] = sv[t];
    out[OUT_BATCH  + g * KSEL + t] = (float)g;
    keep[gi] = 1;
}

// ---------------- Kernel 3: gather x_pooled ----------------
__global__ __launch_bounds__(256)
void k_gather(const float* __restrict__ x, const float* __restrict__ perm_f,
              float* __restrict__ out_x)
{
    const int row  = blockIdx.x * 4 + (threadIdx.x >> 6);
    const int lane = threadIdx.x & 63;
    const int pi = (int)perm_f[row];
    const float4* src = (const float4*)&x[(size_t)pi * CH];
    float4* dst = (float4*)&out_x[(size_t)row * CH];
    dst[lane] = src[lane];
}

// ---------------- Kernel 4: fill edge output with -1 ----------------
__global__ __launch_bounds__(256)
void k_fill(float* __restrict__ out_edge)
{
    const int i = blockIdx.x * blockDim.x + threadIdx.x;
    ((float4*)out_edge)[i] = make_float4(-1.f, -1.f, -1.f, -1.f);
}

// ---------------- Kernel 5: per-block kept-edge counts ----------------
__global__ __launch_bounds__(256)
void k_edgecount(const int* __restrict__ ei, const unsigned char* __restrict__ keep,
                 int* __restrict__ counts)
{
    const int t = threadIdx.x;
    const size_t base = (size_t)blockIdx.x * 4096 + (size_t)t * 16;
    const int* rowp = ei;
    const int* colp = ei + NE;
    int rv[16], cv[16];
    #pragma unroll
    for (int q = 0; q < 4; ++q) {
        int4 r4 = *(const int4*)&rowp[base + q * 4];
        int4 c4 = *(const int4*)&colp[base + q * 4];
        rv[q*4+0]=r4.x; rv[q*4+1]=r4.y; rv[q*4+2]=r4.z; rv[q*4+3]=r4.w;
        cv[q*4+0]=c4.x; cv[q*4+1]=c4.y; cv[q*4+2]=c4.z; cv[q*4+3]=c4.w;
    }
    int cnt = 0;
    #pragma unroll
    for (int q = 0; q < 16; ++q) cnt += (int)(keep[rv[q]] & keep[cv[q]]);

    #pragma unroll
    for (int off = 1; off < 64; off <<= 1) cnt += __shfl_xor(cnt, off, 64);
    __shared__ int wsum[4];
    if ((t & 63) == 0) wsum[t >> 6] = cnt;
    __syncthreads();
    if (t == 0) counts[blockIdx.x] = wsum[0] + wsum[1] + wsum[2] + wsum[3];
}

// ---------------- Kernel 6: exclusive scan of 1024 block counts ----------------
__global__ __launch_bounds__(1024)
void k_scan(const int* __restrict__ counts, int* __restrict__ offsets)
{
    __shared__ int tmp[1024];
    const int t = threadIdx.x;
    const int c = counts[t];
    tmp[t] = c;
    __syncthreads();
    for (int off = 1; off < 1024; off <<= 1) {
        int v = (t >= off) ? tmp[t - off] : 0;
        __syncthreads();
        tmp[t] += v;
        __syncthreads();
    }
    offsets[t] = tmp[t] - c;
}

// ---------------- Kernel 7: stable scatter of kept edges ----------------
__global__ __launch_bounds__(256)
void k_scatter(const int* __restrict__ ei, const unsigned char* __restrict__ keep,
               const int* __restrict__ offsets, float* __restrict__ out_edge)
{
    const int t = threadIdx.x;
    const size_t base = (size_t)blockIdx.x * 4096 + (size_t)t * 16;
    const int* rowp = ei;
    const int* colp = ei + NE;
    int rv[16], cv[16];
    #pragma unroll
    for (int q = 0; q < 4; ++q) {
        int4 r4 = *(const int4*)&rowp[base + q * 4];
        int4 c4 = *(const int4*)&colp[base + q * 4];
        rv[q*4+0]=r4.x; rv[q*4+1]=r4.y; rv[q*4+2]=r4.z; rv[q*4+3]=r4.w;
        cv[q*4+0]=c4.x; cv[q*4+1]=c4.y; cv[q*4+2]=c4.z; cv[q*4+3]=c4.w;
    }
    unsigned m = 0; int cnt = 0;
    #pragma unroll
    for (int q = 0; q < 16; ++q) {
        const bool kk = keep[rv[q]] && keep[cv[q]];
        m |= ((unsigned)kk) << q;
        cnt += (int)kk;
    }
    // exclusive scan over the block's 256 threads (thread chunks are contiguous
    // in edge order, so this preserves the stable original ordering)
    const int lane = t & 63, w = t >> 6;
    int incl = cnt;
    #pragma unroll
    for (int off = 1; off < 64; off <<= 1) {
        int v = __shfl_up(incl, off, 64);
        if (lane >= off) incl += v;
    }
    __shared__ int wtot[4];
    if (lane == 63) wtot[w] = incl;
    __syncthreads();
    int wbase = 0;
    for (int i = 0; i < w; ++i) wbase += wtot[i];
    int pos = offsets[blockIdx.x] + wbase + (incl - cnt);
    #pragma unroll
    for (int q = 0; q < 16; ++q) {
        if (m & (1u << q)) {
            out_edge[pos]      = (float)rv[q];
            out_edge[NE + pos] = (float)cv[q];
            ++pos;
        }
    }
}

extern "C" void kernel_launch(void* const* d_in, const int* in_sizes, int n_in,
                              void* d_out, int out_size, void* d_ws, size_t ws_size,
                              hipStream_t stream)
{
    const float* x  = (const float*)d_in[0];
    const int*   ei = (const int*)d_in[1];
    // d_in[2] (batch) is implied by the static layout; unused
    const float* W1 = (const float*)d_in[3];
    const float* b1 = (const float*)d_in[4];
    const float* W2 = (const float*)d_in[5];
    const float* b2 = (const float*)d_in[6];

    float* out = (float*)d_out;
    char*  ws  = (char*)d_ws;
    float*         scores  = (float*)(ws + WS_SCORES);
    unsigned char* keep    = (unsigned char*)(ws + WS_KEEP);
    int*           counts  = (int*)(ws + WS_COUNTS);
    int*           offsets = (int*)(ws + WS_OFFSETS);

    hipMemsetAsync(keep, 0, NN, stream);

    k_scores<<<NN / 64, 256, 0, stream>>>(x, W1, b1, W2, b2, scores);
    k_topk<<<NG, 512, 0, stream>>>(scores, out, keep);
    k_gather<<<(NG * KSEL) / 4, 256, 0, stream>>>(x, out + OUT_PERM, out + OUT_X);
    k_fill<<<(2 * NE) / (4 * 256), 256, 0, stream>>>(out + OUT_EDGE);
    k_edgecount<<<NE / 4096, 256, 0, stream>>>(ei, keep, counts);
    k_scan<<<1, 1024, 0, stream>>>(counts, offsets);
    k_scatter<<<NE / 4096, 256, 0, stream>>>(ei, keep, offsets, out + OUT_EDGE);
}

// Round 2
// 441.976 us; speedup vs baseline: 1.3175x; 1.3175x over previous
//
#include <hip/hip_runtime.h>
#include <hip/hip_bf16.h>

// Problem constants (static graph layout from the reference)
#define NG 128          // graphs
#define NPG 1024        // nodes per graph
#define NN (NG * NPG)   // 131072 nodes
#define NE (NN * 32)    // 4194304 edges
#define CH 256          // channels
#define KSEL 512        // top-k per graph

// Output layout (all float32, concatenated flat in return order)
#define OUT_X      0
#define OUT_EDGE   16777216   // 65536*256
#define OUT_BATCH  25165824   // + 2*4194304
#define OUT_PERM   25231360
#define OUT_SCORES 25296896
// total 25362432 floats

// Workspace layout (bytes)
#define WS_SCORES  0
#define WS_KEEP    524288
#define WS_COUNTS  655360
#define WS_OFFSETS 659456

// ---------------- Kernel 1: scores = tanh(x@W1 + b1) @ W2 + b2 ----------------
// 32 nodes/block, 256 threads (4 waves). Wave w owns nodes 8w..8w+7; lane l owns
// output cols 4l..4l+3 -> acc[8][4] fp32 in VGPRs.
// LDS: W1 chunk [16][256] (16 KiB) + X chunk [32][16] (2 KiB) = 18.25 KiB
//   -> ~4-5 blocks/CU (vs 1 before: the whole point of this rewrite).
// Inner 4-k step: 4x ds_read_b128 (W1 row slice, 64 lanes cover contiguous 1KiB,
// conflict-free) + 8x same-address ds_read_b128 broadcast (x) + 128 FMA.
__global__ __launch_bounds__(256, 4)
void k_scores(const float* __restrict__ x, const float* __restrict__ W1,
              const float* __restrict__ b1, const float* __restrict__ W2,
              const float* __restrict__ b2, float* __restrict__ scores)
{
    __shared__ __align__(16) float W1s[16][CH];  // 16 KiB
    __shared__ __align__(16) float Xs[32][16];   // 2 KiB

    const int tid = threadIdx.x;
    const int w_  = tid >> 6;
    const int l   = tid & 63;
    const int n0  = blockIdx.x * 32;

    // staging assignment for X chunk (first 128 threads): node tid>>2, 4 floats
    const bool xa = (tid < 128);
    const int  xn = tid >> 2;          // 0..31
    const int  xc = (tid & 3) * 4;     // 0,4,8,12

    // acc init = b1 slice (per-lane cols 4l..4l+3)
    const float4 b1v = *(const float4*)&b1[l * 4];
    float acc[8][4];
    #pragma unroll
    for (int n = 0; n < 8; ++n) {
        acc[n][0] = b1v.x; acc[n][1] = b1v.y; acc[n][2] = b1v.z; acc[n][3] = b1v.w;
    }

    // register prefetch of chunk 0
    float4 wreg[4];
    float4 xreg = make_float4(0.f, 0.f, 0.f, 0.f);
    {
        const float4* w1f4 = (const float4*)W1;   // chunk 0 base
        #pragma unroll
        for (int it = 0; it < 4; ++it) wreg[it] = w1f4[it * 256 + tid];
        if (xa) xreg = *(const float4*)&x[(size_t)(n0 + xn) * CH + xc];
    }

    for (int kc = 0; kc < 16; ++kc) {
        __syncthreads();   // previous chunk's compute done before overwrite
        // commit staged regs to LDS (coalesced, conflict-free)
        #pragma unroll
        for (int it = 0; it < 4; ++it)
            ((float4*)W1s)[it * 256 + tid] = wreg[it];
        if (xa) *(float4*)&Xs[xn][xc] = xreg;
        __syncthreads();

        // prefetch next chunk while computing this one
        if (kc + 1 < 16) {
            const float4* w1f4 = (const float4*)(W1 + (size_t)(kc + 1) * 16 * CH);
            #pragma unroll
            for (int it = 0; it < 4; ++it) wreg[it] = w1f4[it * 256 + tid];
            if (xa) xreg = *(const float4*)&x[(size_t)(n0 + xn) * CH + (kc + 1) * 16 + xc];
        }

        #pragma unroll
        for (int kq = 0; kq < 4; ++kq) {
            const int k4 = kq * 4;
            const float4 wv0 = *(const float4*)&W1s[k4 + 0][l * 4];
            const float4 wv1 = *(const float4*)&W1s[k4 + 1][l * 4];
            const float4 wv2 = *(const float4*)&W1s[k4 + 2][l * 4];
            const float4 wv3 = *(const float4*)&W1s[k4 + 3][l * 4];
            #pragma unroll
            for (int n = 0; n < 8; ++n) {
                const float4 xv = *(const float4*)&Xs[w_ * 8 + n][k4];  // wave-uniform addr: LDS broadcast
                acc[n][0] = fmaf(xv.x, wv0.x, acc[n][0]);
                acc[n][1] = fmaf(xv.x, wv0.y, acc[n][1]);
                acc[n][2] = fmaf(xv.x, wv0.z, acc[n][2]);
                acc[n][3] = fmaf(xv.x, wv0.w, acc[n][3]);
                acc[n][0] = fmaf(xv.y, wv1.x, acc[n][0]);
                acc[n][1] = fmaf(xv.y, wv1.y, acc[n][1]);
                acc[n][2] = fmaf(xv.y, wv1.z, acc[n][2]);
                acc[n][3] = fmaf(xv.y, wv1.w, acc[n][3]);
                acc[n][0] = fmaf(xv.z, wv2.x, acc[n][0]);
                acc[n][1] = fmaf(xv.z, wv2.y, acc[n][1]);
                acc[n][2] = fmaf(xv.z, wv2.z, acc[n][2]);
                acc[n][3] = fmaf(xv.z, wv2.w, acc[n][3]);
                acc[n][0] = fmaf(xv.w, wv3.x, acc[n][0]);
                acc[n][1] = fmaf(xv.w, wv3.y, acc[n][1]);
                acc[n][2] = fmaf(xv.w, wv3.z, acc[n][2]);
                acc[n][3] = fmaf(xv.w, wv3.w, acc[n][3]);
            }
        }
    }

    // epilogue: tanh, dot with W2 slice, 64-lane reduce per node
    const float4 w2v = *(const float4*)&W2[l * 4];
    const float  bb  = b2[0];
    float s_[8];
    #pragma unroll
    for (int n = 0; n < 8; ++n) {
        s_[n] = tanhf(acc[n][0]) * w2v.x + tanhf(acc[n][1]) * w2v.y
              + tanhf(acc[n][2]) * w2v.z + tanhf(acc[n][3]) * w2v.w;
    }
    #pragma unroll
    for (int off = 1; off < 64; off <<= 1)
        #pragma unroll
        for (int n = 0; n < 8; ++n)
            s_[n] += __shfl_xor(s_[n], off, 64);

    if (l == 0) {
        #pragma unroll
        for (int n = 0; n < 8; ++n)
            scores[n0 + w_ * 8 + n] = s_[n] + bb;
    }
}

// ---------------- Kernel 2: per-graph bitonic top-k (full sort of 1024) -------
__global__ __launch_bounds__(512)
void k_topk(const float* __restrict__ scores, float* __restrict__ out,
            unsigned char* __restrict__ keep)
{
    __shared__ float sv[1024];
    __shared__ int   si[1024];
    const int g = blockIdx.x;
    const int t = threadIdx.x;
    sv[t]       = scores[g * NPG + t];       si[t]       = t;
    sv[t + 512] = scores[g * NPG + t + 512]; si[t + 512] = t + 512;

    for (int size = 2; size <= 1024; size <<= 1) {
        for (int stride = size >> 1; stride > 0; stride >>= 1) {
            __syncthreads();
            const int lo = ((t & ~(stride - 1)) << 1) | (t & (stride - 1));
            const int hi = lo + stride;
            const bool dirDesc = ((lo & size) == 0);
            const float va = sv[lo], vb = sv[hi];
            const int ia = si[lo], ib = si[hi];
            const bool aB = (va > vb) || (va == vb && ia < ib);
            if (aB != dirDesc) {
                sv[lo] = vb; sv[hi] = va;
                si[lo] = ib; si[hi] = ia;
            }
        }
    }
    __syncthreads();
    // rank t of this graph survives (t in [0,512))
    const int gi = g * NPG + si[t];
    out[OUT_PERM   + g * KSEL + t] = (float)gi;
    out[OUT_SCORES + g * KSEL + t] = sv[t];
    out[OUT_BATCH  + g * KSEL + t] = (float)g;
    keep[gi] = 1;
}

// ---------------- Kernel 3: gather x_pooled ----------------
__global__ __launch_bounds__(256)
void k_gather(const float* __restrict__ x, const float* __restrict__ perm_f,
              float* __restrict__ out_x)
{
    const int row  = blockIdx.x * 4 + (threadIdx.x >> 6);
    const int lane = threadIdx.x & 63;
    const int pi = (int)perm_f[row];
    const float4* src = (const float4*)&x[(size_t)pi * CH];
    float4* dst = (float4*)&out_x[(size_t)row * CH];
    dst[lane] = src[lane];
}

// ---------------- Kernel 4: fill edge output with -1 ----------------
__global__ __launch_bounds__(256)
void k_fill(float* __restrict__ out_edge)
{
    const int i = blockIdx.x * blockDim.x + threadIdx.x;
    ((float4*)out_edge)[i] = make_float4(-1.f, -1.f, -1.f, -1.f);
}

// ---------------- Kernel 5: per-block kept-edge counts ----------------
__global__ __launch_bounds__(256)
void k_edgecount(const int* __restrict__ ei, const unsigned char* __restrict__ keep,
                 int* __restrict__ counts)
{
    const int t = threadIdx.x;
    const size_t base = (size_t)blockIdx.x * 4096 + (size_t)t * 16;
    const int* rowp = ei;
    const int* colp = ei + NE;
    int rv[16], cv[16];
    #pragma unroll
    for (int q = 0; q < 4; ++q) {
        int4 r4 = *(const int4*)&rowp[base + q * 4];
        int4 c4 = *(const int4*)&colp[base + q * 4];
        rv[q*4+0]=r4.x; rv[q*4+1]=r4.y; rv[q*4+2]=r4.z; rv[q*4+3]=r4.w;
        cv[q*4+0]=c4.x; cv[q*4+1]=c4.y; cv[q*4+2]=c4.z; cv[q*4+3]=c4.w;
    }
    int cnt = 0;
    #pragma unroll
    for (int q = 0; q < 16; ++q) cnt += (int)(keep[rv[q]] & keep[cv[q]]);

    #pragma unroll
    for (int off = 1; off < 64; off <<= 1) cnt += __shfl_xor(cnt, off, 64);
    __shared__ int wsum[4];
    if ((t & 63) == 0) wsum[t >> 6] = cnt;
    __syncthreads();
    if (t == 0) counts[blockIdx.x] = wsum[0] + wsum[1] + wsum[2] + wsum[3];
}

// ---------------- Kernel 6: exclusive scan of 1024 block counts ----------------
__global__ __launch_bounds__(1024)
void k_scan(const int* __restrict__ counts, int* __restrict__ offsets)
{
    __shared__ int tmp[1024];
    const int t = threadIdx.x;
    const int c = counts[t];
    tmp[t] = c;
    __syncthreads();
    for (int off = 1; off < 1024; off <<= 1) {
        int v = (t >= off) ? tmp[t - off] : 0;
        __syncthreads();
        tmp[t] += v;
        __syncthreads();
    }
    offsets[t] = tmp[t] - c;
}

// ---------------- Kernel 7: stable scatter of kept edges ----------------
__global__ __launch_bounds__(256)
void k_scatter(const int* __restrict__ ei, const unsigned char* __restrict__ keep,
               const int* __restrict__ offsets, float* __restrict__ out_edge)
{
    const int t = threadIdx.x;
    const size_t base = (size_t)blockIdx.x * 4096 + (size_t)t * 16;
    const int* rowp = ei;
    const int* colp = ei + NE;
    int rv[16], cv[16];
    #pragma unroll
    for (int q = 0; q < 4; ++q) {
        int4 r4 = *(const int4*)&rowp[base + q * 4];
        int4 c4 = *(const int4*)&colp[base + q * 4];
        rv[q*4+0]=r4.x; rv[q*4+1]=r4.y; rv[q*4+2]=r4.z; rv[q*4+3]=r4.w;
        cv[q*4+0]=c4.x; cv[q*4+1]=c4.y; cv[q*4+2]=c4.z; cv[q*4+3]=c4.w;
    }
    unsigned m = 0; int cnt = 0;
    #pragma unroll
    for (int q = 0; q < 16; ++q) {
        const bool kk = keep[rv[q]] && keep[cv[q]];
        m |= ((unsigned)kk) << q;
        cnt += (int)kk;
    }
    // exclusive scan over the block's 256 threads (thread chunks are contiguous
    // in edge order, so this preserves the stable original ordering)
    const int lane = t & 63, w = t >> 6;
    int incl = cnt;
    #pragma unroll
    for (int off = 1; off < 64; off <<= 1) {
        int v = __shfl_up(incl, off, 64);
        if (lane >= off) incl += v;
    }
    __shared__ int wtot[4];
    if (lane == 63) wtot[w] = incl;
    __syncthreads();
    int wbase = 0;
    for (int i = 0; i < w; ++i) wbase += wtot[i];
    int pos = offsets[blockIdx.x] + wbase + (incl - cnt);
    #pragma unroll
    for (int q = 0; q < 16; ++q) {
        if (m & (1u << q)) {
            out_edge[pos]      = (float)rv[q];
            out_edge[NE + pos] = (float)cv[q];
            ++pos;
        }
    }
}

extern "C" void kernel_launch(void* const* d_in, const int* in_sizes, int n_in,
                              void* d_out, int out_size, void* d_ws, size_t ws_size,
                              hipStream_t stream)
{
    const float* x  = (const float*)d_in[0];
    const int*   ei = (const int*)d_in[1];
    // d_in[2] (batch) is implied by the static layout; unused
    const float* W1 = (const float*)d_in[3];
    const float* b1 = (const float*)d_in[4];
    const float* W2 = (const float*)d_in[5];
    const float* b2 = (const float*)d_in[6];

    float* out = (float*)d_out;
    char*  ws  = (char*)d_ws;
    float*         scores  = (float*)(ws + WS_SCORES);
    unsigned char* keep    = (unsigned char*)(ws + WS_KEEP);
    int*           counts  = (int*)(ws + WS_COUNTS);
    int*           offsets = (int*)(ws + WS_OFFSETS);

    hipMemsetAsync(keep, 0, NN, stream);

    k_scores<<<NN / 32, 256, 0, stream>>>(x, W1, b1, W2, b2, scores);
    k_topk<<<NG, 512, 0, stream>>>(scores, out, keep);
    k_gather<<<(NG * KSEL) / 4, 256, 0, stream>>>(x, out + OUT_PERM, out + OUT_X);
    k_fill<<<(2 * NE) / (4 * 256), 256, 0, stream>>>(out + OUT_EDGE);
    k_edgecount<<<NE / 4096, 256, 0, stream>>>(ei, keep, counts);
    k_scan<<<1, 1024, 0, stream>>>(counts, offsets);
    k_scatter<<<NE / 4096, 256, 0, stream>>>(ei, keep, offsets, out + OUT_EDGE);
}

// Round 3
// 331.700 us; speedup vs baseline: 1.7556x; 1.3325x over previous
//
#include <hip/hip_runtime.h>
#include <hip/hip_bf16.h>

// Problem constants (static graph layout from the reference)
#define NG 128          // graphs
#define NPG 1024        // nodes per graph
#define NN (NG * NPG)   // 131072 nodes
#define NE (NN * 32)    // 4194304 edges
#define CH 256          // channels
#define KSEL 512        // top-k per graph

// Output layout (all float32, concatenated flat in return order)
#define OUT_X      0
#define OUT_EDGE   16777216   // 65536*256
#define OUT_BATCH  25165824   // + 2*4194304
#define OUT_PERM   25231360
#define OUT_SCORES 25296896
// total 25362432 floats

// Workspace layout (bytes)
#define WS_SCORES  0
#define WS_KEEP    524288
#define WS_COUNTS  655360
#define WS_OFFSETS 659456

// ---------------- Kernel 1: scores = tanh(x@W1 + b1) @ W2 + b2 ----------------
// 32 nodes/block, 256 threads (4 waves). Wave w owns nodes 8w..8w+7; lane l owns
// output cols 4l..4l+3 -> acc[8][4] fp32 in VGPRs.
// Staging via global_load_lds (width 16): no staging registers -> no spill
// (R2's __launch_bounds__(256,4) forced 64 VGPRs and spilled ~500 MB to scratch).
// LDS: W1 chunk [16][256] (16 KiB) + X chunk [32][16] (2 KiB) = 18.25 KiB.
__global__ __launch_bounds__(256, 2)
void k_scores(const float* __restrict__ x, const float* __restrict__ W1,
              const float* __restrict__ b1, const float* __restrict__ W2,
              const float* __restrict__ b2, float* __restrict__ scores)
{
    __shared__ __align__(16) float W1s[16][CH];  // 16 KiB
    __shared__ __align__(16) float Xs[32][16];   // 2 KiB

    const int tid = threadIdx.x;
    const int w_  = tid >> 6;
    const int l   = tid & 63;
    const int n0  = blockIdx.x * 32;

    // acc init = b1 slice (per-lane cols 4l..4l+3)
    const float4 b1v = *(const float4*)&b1[l * 4];
    float acc[8][4];
    #pragma unroll
    for (int n = 0; n < 8; ++n) {
        acc[n][0] = b1v.x; acc[n][1] = b1v.y; acc[n][2] = b1v.z; acc[n][3] = b1v.w;
    }

    for (int kc = 0; kc < 16; ++kc) {
        __syncthreads();   // previous chunk's compute done before overwrite

        // ---- async global -> LDS staging (wave-uniform LDS base + lane*16) ----
        // W1 chunk: 16 rows x 256 cols = 16 KiB = 16 wave-loads of 1 KiB
        #pragma unroll
        for (int it = 0; it < 4; ++it) {
            const float* g = W1 + (size_t)kc * (16 * CH) + (w_ * 4 + it) * CH + l * 4;
            float* lb = &W1s[0][0] + (w_ * 4 + it) * CH;   // uniform per wave
            __builtin_amdgcn_global_load_lds(
                (const __attribute__((address_space(1))) void*)g,
                (__attribute__((address_space(3))) void*)lb, 16, 0, 0);
        }
        // X chunk: 32 rows x 16 cols = 2 KiB = 2 wave-loads (waves 0,1)
        if (w_ < 2) {
            const float* g = x + (size_t)(n0 + w_ * 16 + (l >> 2)) * CH + kc * 16 + (l & 3) * 4;
            float* lb = &Xs[0][0] + w_ * 256;              // uniform per wave
            __builtin_amdgcn_global_load_lds(
                (const __attribute__((address_space(1))) void*)g,
                (__attribute__((address_space(3))) void*)lb, 16, 0, 0);
        }
        __syncthreads();   // compiler drains vmcnt(0) before this barrier

        #pragma unroll
        for (int kq = 0; kq < 4; ++kq) {
            const int k4 = kq * 4;
            const float4 wv0 = *(const float4*)&W1s[k4 + 0][l * 4];
            const float4 wv1 = *(const float4*)&W1s[k4 + 1][l * 4];
            const float4 wv2 = *(const float4*)&W1s[k4 + 2][l * 4];
            const float4 wv3 = *(const float4*)&W1s[k4 + 3][l * 4];
            #pragma unroll
            for (int n = 0; n < 8; ++n) {
                const float4 xv = *(const float4*)&Xs[w_ * 8 + n][k4];  // wave-uniform addr: LDS broadcast
                acc[n][0] = fmaf(xv.x, wv0.x, acc[n][0]);
                acc[n][1] = fmaf(xv.x, wv0.y, acc[n][1]);
                acc[n][2] = fmaf(xv.x, wv0.z, acc[n][2]);
                acc[n][3] = fmaf(xv.x, wv0.w, acc[n][3]);
                acc[n][0] = fmaf(xv.y, wv1.x, acc[n][0]);
                acc[n][1] = fmaf(xv.y, wv1.y, acc[n][1]);
                acc[n][2] = fmaf(xv.y, wv1.z, acc[n][2]);
                acc[n][3] = fmaf(xv.y, wv1.w, acc[n][3]);
                acc[n][0] = fmaf(xv.z, wv2.x, acc[n][0]);
                acc[n][1] = fmaf(xv.z, wv2.y, acc[n][1]);
                acc[n][2] = fmaf(xv.z, wv2.z, acc[n][2]);
                acc[n][3] = fmaf(xv.z, wv2.w, acc[n][3]);
                acc[n][0] = fmaf(xv.w, wv3.x, acc[n][0]);
                acc[n][1] = fmaf(xv.w, wv3.y, acc[n][1]);
                acc[n][2] = fmaf(xv.w, wv3.z, acc[n][2]);
                acc[n][3] = fmaf(xv.w, wv3.w, acc[n][3]);
            }
        }
    }

    // epilogue: tanh, dot with W2 slice, 64-lane reduce per node
    const float4 w2v = *(const float4*)&W2[l * 4];
    const float  bb  = b2[0];
    float s_[8];
    #pragma unroll
    for (int n = 0; n < 8; ++n) {
        s_[n] = tanhf(acc[n][0]) * w2v.x + tanhf(acc[n][1]) * w2v.y
              + tanhf(acc[n][2]) * w2v.z + tanhf(acc[n][3]) * w2v.w;
    }
    #pragma unroll
    for (int off = 1; off < 64; off <<= 1)
        #pragma unroll
        for (int n = 0; n < 8; ++n)
            s_[n] += __shfl_xor(s_[n], off, 64);

    if (l == 0) {
        #pragma unroll
        for (int n = 0; n < 8; ++n)
            scores[n0 + w_ * 8 + n] = s_[n] + bb;
    }
}

// ---------------- Kernel 2: per-graph bitonic top-k (full sort of 1024) -------
__global__ __launch_bounds__(512)
void k_topk(const float* __restrict__ scores, float* __restrict__ out,
            unsigned char* __restrict__ keep)
{
    __shared__ float sv[1024];
    __shared__ int   si[1024];
    const int g = blockIdx.x;
    const int t = threadIdx.x;
    sv[t]       = scores[g * NPG + t];       si[t]       = t;
    sv[t + 512] = scores[g * NPG + t + 512]; si[t + 512] = t + 512;

    for (int size = 2; size <= 1024; size <<= 1) {
        for (int stride = size >> 1; stride > 0; stride >>= 1) {
            __syncthreads();
            const int lo = ((t & ~(stride - 1)) << 1) | (t & (stride - 1));
            const int hi = lo + stride;
            const bool dirDesc = ((lo & size) == 0);
            const float va = sv[lo], vb = sv[hi];
            const int ia = si[lo], ib = si[hi];
            const bool aB = (va > vb) || (va == vb && ia < ib);
            if (aB != dirDesc) {
                sv[lo] = vb; sv[hi] = va;
                si[lo] = ib; si[hi] = ia;
            }
        }
    }
    __syncthreads();
    // rank t of this graph survives (t in [0,512))
    const int gi = g * NPG + si[t];
    out[OUT_PERM   + g * KSEL + t] = (float)gi;
    out[OUT_SCORES + g * KSEL + t] = sv[t];
    out[OUT_BATCH  + g * KSEL + t] = (float)g;
    keep[gi] = 1;
}

// ---------------- Kernel 3: gather x_pooled ----------------
__global__ __launch_bounds__(256)
void k_gather(const float* __restrict__ x, const float* __restrict__ perm_f,
              float* __restrict__ out_x)
{
    const int row  = blockIdx.x * 4 + (threadIdx.x >> 6);
    const int lane = threadIdx.x & 63;
    const int pi = (int)perm_f[row];
    const float4* src = (const float4*)&x[(size_t)pi * CH];
    float4* dst = (float4*)&out_x[(size_t)row * CH];
    dst[lane] = src[lane];
}

// ---------------- Kernel 4: fill edge output with -1 ----------------
__global__ __launch_bounds__(256)
void k_fill(float* __restrict__ out_edge)
{
    const int i = blockIdx.x * blockDim.x + threadIdx.x;
    ((float4*)out_edge)[i] = make_float4(-1.f, -1.f, -1.f, -1.f);
}

// ---------------- Kernel 5: per-block kept-edge counts ----------------
__global__ __launch_bounds__(256)
void k_edgecount(const int* __restrict__ ei, const unsigned char* __restrict__ keep,
                 int* __restrict__ counts)
{
    const int t = threadIdx.x;
    const size_t base = (size_t)blockIdx.x * 4096 + (size_t)t * 16;
    const int* rowp = ei;
    const int* colp = ei + NE;
    int rv[16], cv[16];
    #pragma unroll
    for (int q = 0; q < 4; ++q) {
        int4 r4 = *(const int4*)&rowp[base + q * 4];
        int4 c4 = *(const int4*)&colp[base + q * 4];
        rv[q*4+0]=r4.x; rv[q*4+1]=r4.y; rv[q*4+2]=r4.z; rv[q*4+3]=r4.w;
        cv[q*4+0]=c4.x; cv[q*4+1]=c4.y; cv[q*4+2]=c4.z; cv[q*4+3]=c4.w;
    }
    int cnt = 0;
    #pragma unroll
    for (int q = 0; q < 16; ++q) cnt += (int)(keep[rv[q]] & keep[cv[q]]);

    #pragma unroll
    for (int off = 1; off < 64; off <<= 1) cnt += __shfl_xor(cnt, off, 64);
    __shared__ int wsum[4];
    if ((t & 63) == 0) wsum[t >> 6] = cnt;
    __syncthreads();
    if (t == 0) counts[blockIdx.x] = wsum[0] + wsum[1] + wsum[2] + wsum[3];
}

// ---------------- Kernel 6: exclusive scan of 1024 block counts ----------------
__global__ __launch_bounds__(1024)
void k_scan(const int* __restrict__ counts, int* __restrict__ offsets)
{
    __shared__ int tmp[1024];
    const int t = threadIdx.x;
    const int c = counts[t];
    tmp[t] = c;
    __syncthreads();
    for (int off = 1; off < 1024; off <<= 1) {
        int v = (t >= off) ? tmp[t - off] : 0;
        __syncthreads();
        tmp[t] += v;
        __syncthreads();
    }
    offsets[t] = tmp[t] - c;
}

// ---------------- Kernel 7: stable scatter of kept edges ----------------
__global__ __launch_bounds__(256)
void k_scatter(const int* __restrict__ ei, const unsigned char* __restrict__ keep,
               const int* __restrict__ offsets, float* __restrict__ out_edge)
{
    const int t = threadIdx.x;
    const size_t base = (size_t)blockIdx.x * 4096 + (size_t)t * 16;
    const int* rowp = ei;
    const int* colp = ei + NE;
    int rv[16], cv[16];
    #pragma unroll
    for (int q = 0; q < 4; ++q) {
        int4 r4 = *(const int4*)&rowp[base + q * 4];
        int4 c4 = *(const int4*)&colp[base + q * 4];
        rv[q*4+0]=r4.x; rv[q*4+1]=r4.y; rv[q*4+2]=r4.z; rv[q*4+3]=r4.w;
        cv[q*4+0]=c4.x; cv[q*4+1]=c4.y; cv[q*4+2]=c4.z; cv[q*4+3]=c4.w;
    }
    unsigned m = 0; int cnt = 0;
    #pragma unroll
    for (int q = 0; q < 16; ++q) {
        const bool kk = keep[rv[q]] && keep[cv[q]];
        m |= ((unsigned)kk) << q;
        cnt += (int)kk;
    }
    // exclusive scan over the block's 256 threads (thread chunks are contiguous
    // in edge order, so this preserves the stable original ordering)
    const int lane = t & 63, w = t >> 6;
    int incl = cnt;
    #pragma unroll
    for (int off = 1; off < 64; off <<= 1) {
        int v = __shfl_up(incl, off, 64);
        if (lane >= off) incl += v;
    }
    __shared__ int wtot[4];
    if (lane == 63) wtot[w] = incl;
    __syncthreads();
    int wbase = 0;
    for (int i = 0; i < w; ++i) wbase += wtot[i];
    int pos = offsets[blockIdx.x] + wbase + (incl - cnt);
    #pragma unroll
    for (int q = 0; q < 16; ++q) {
        if (m & (1u << q)) {
            out_edge[pos]      = (float)rv[q];
            out_edge[NE + pos] = (float)cv[q];
            ++pos;
        }
    }
}

extern "C" void kernel_launch(void* const* d_in, const int* in_sizes, int n_in,
                              void* d_out, int out_size, void* d_ws, size_t ws_size,
                              hipStream_t stream)
{
    const float* x  = (const float*)d_in[0];
    const int*   ei = (const int*)d_in[1];
    // d_in[2] (batch) is implied by the static layout; unused
    const float* W1 = (const float*)d_in[3];
    const float* b1 = (const float*)d_in[4];
    const float* W2 = (const float*)d_in[5];
    const float* b2 = (const float*)d_in[6];

    float* out = (float*)d_out;
    char*  ws  = (char*)d_ws;
    float*         scores  = (float*)(ws + WS_SCORES);
    unsigned char* keep    = (unsigned char*)(ws + WS_KEEP);
    int*           counts  = (int*)(ws + WS_COUNTS);
    int*           offsets = (int*)(ws + WS_OFFSETS);

    hipMemsetAsync(keep, 0, NN, stream);

    k_scores<<<NN / 32, 256, 0, stream>>>(x, W1, b1, W2, b2, scores);
    k_topk<<<NG, 512, 0, stream>>>(scores, out, keep);
    k_gather<<<(NG * KSEL) / 4, 256, 0, stream>>>(x, out + OUT_PERM, out + OUT_X);
    k_fill<<<(2 * NE) / (4 * 256), 256, 0, stream>>>(out + OUT_EDGE);
    k_edgecount<<<NE / 4096, 256, 0, stream>>>(ei, keep, counts);
    k_scan<<<1, 1024, 0, stream>>>(counts, offsets);
    k_scatter<<<NE / 4096, 256, 0, stream>>>(ei, keep, offsets, out + OUT_EDGE);
}

// Round 4
// 327.359 us; speedup vs baseline: 1.7788x; 1.0133x over previous
//
#include <hip/hip_runtime.h>
#include <hip/hip_bf16.h>

// Problem constants (static graph layout from the reference)
#define NG 128          // graphs
#define NPG 1024        // nodes per graph
#define NN (NG * NPG)   // 131072 nodes
#define NE (NN * 32)    // 4194304 edges
#define CH 256          // channels
#define KSEL 512        // top-k per graph

// Output layout (all float32, concatenated flat in return order)
#define OUT_X      0
#define OUT_EDGE   16777216   // 65536*256
#define OUT_BATCH  25165824   // + 2*4194304
#define OUT_PERM   25231360
#define OUT_SCORES 25296896
// total 25362432 floats

// Workspace layout (bytes)
#define WS_SCORES  0           // 131072 floats = 524288 B
#define WS_KEEP    524288      // bit-packed: 131072 bits = 16384 B (L1-resident!)
#define WS_COUNTS  540672      // 1024 ints
#define WS_OFFSETS 544768      // 1024 ints

// ---------------- Kernel 1: scores = tanh(x@W1 + b1) @ W2 + b2 ----------------
// 32 nodes/block, 256 threads (4 waves). Wave w owns nodes 8w..8w+7; lane l owns
// output cols 4l..4l+3 -> acc[8][4] fp32 in VGPRs.
// Double-buffered global_load_lds staging: stage(k+1) issued BEFORE compute(k),
// so the compiler's vmcnt(0) drain at the barrier lands ~1024 FMA-cycles after
// issue -> HBM latency (~900 cyc) covered. One barrier per chunk.
// LDS: 2 x (W1[16][256] 16KiB + X[32][16] 2KiB) = 36.5 KiB -> 4 blocks/CU.
__global__ __launch_bounds__(256, 2)
void k_scores(const float* __restrict__ x, const float* __restrict__ W1,
              const float* __restrict__ b1, const float* __restrict__ W2,
              const float* __restrict__ b2, float* __restrict__ scores)
{
    __shared__ __align__(16) float W1s[2][16][CH];  // 2 x 16 KiB
    __shared__ __align__(16) float Xs[2][32][16];   // 2 x 2 KiB

    const int tid = threadIdx.x;
    const int w_  = tid >> 6;
    const int l   = tid & 63;
    const int n0  = blockIdx.x * 32;

    // acc init = b1 slice (per-lane cols 4l..4l+3)
    const float4 b1v = *(const float4*)&b1[l * 4];
    float acc[8][4];
    #pragma unroll
    for (int n = 0; n < 8; ++n) {
        acc[n][0] = b1v.x; acc[n][1] = b1v.y; acc[n][2] = b1v.z; acc[n][3] = b1v.w;
    }

    // async stage of chunk kc into buffer b (wave-uniform LDS base + lane*16)
    #define STAGE(kc_, b_)                                                          \
    do {                                                                            \
        _Pragma("unroll")                                                           \
        for (int it = 0; it < 4; ++it) {                                            \
            const float* g = W1 + (size_t)(kc_) * (16 * CH) + (w_ * 4 + it) * CH + l * 4; \
            float* lb = &W1s[b_][0][0] + (w_ * 4 + it) * CH;                        \
            __builtin_amdgcn_global_load_lds(                                       \
                (const __attribute__((address_space(1))) void*)g,                   \
                (__attribute__((address_space(3))) void*)lb, 16, 0, 0);             \
        }                                                                           \
        if (w_ < 2) {                                                               \
            const float* g = x + (size_t)(n0 + w_ * 16 + (l >> 2)) * CH + (kc_) * 16 + (l & 3) * 4; \
            float* lb = &Xs[b_][0][0] + w_ * 256;                                   \
            __builtin_amdgcn_global_load_lds(                                       \
                (const __attribute__((address_space(1))) void*)g,                   \
                (__attribute__((address_space(3))) void*)lb, 16, 0, 0);             \
        }                                                                           \
    } while (0)

    STAGE(0, 0);
    __syncthreads();   // one full drain for the prologue

    for (int kc = 0; kc < 16; ++kc) {
        const int cur = kc & 1;
        if (kc + 1 < 16) STAGE(kc + 1, cur ^ 1);   // prefetch overlaps compute below

        #pragma unroll
        for (int kq = 0; kq < 4; ++kq) {
            const int k4 = kq * 4;
            const float4 wv0 = *(const float4*)&W1s[cur][k4 + 0][l * 4];
            const float4 wv1 = *(const float4*)&W1s[cur][k4 + 1][l * 4];
            const float4 wv2 = *(const float4*)&W1s[cur][k4 + 2][l * 4];
            const float4 wv3 = *(const float4*)&W1s[cur][k4 + 3][l * 4];
            #pragma unroll
            for (int n = 0; n < 8; ++n) {
                const float4 xv = *(const float4*)&Xs[cur][w_ * 8 + n][k4];  // wave-uniform: LDS broadcast
                acc[n][0] = fmaf(xv.x, wv0.x, acc[n][0]);
                acc[n][1] = fmaf(xv.x, wv0.y, acc[n][1]);
                acc[n][2] = fmaf(xv.x, wv0.z, acc[n][2]);
                acc[n][3] = fmaf(xv.x, wv0.w, acc[n][3]);
                acc[n][0] = fmaf(xv.y, wv1.x, acc[n][0]);
                acc[n][1] = fmaf(xv.y, wv1.y, acc[n][1]);
                acc[n][2] = fmaf(xv.y, wv1.z, acc[n][2]);
                acc[n][3] = fmaf(xv.y, wv1.w, acc[n][3]);
                acc[n][0] = fmaf(xv.z, wv2.x, acc[n][0]);
                acc[n][1] = fmaf(xv.z, wv2.y, acc[n][1]);
                acc[n][2] = fmaf(xv.z, wv2.z, acc[n][2]);
                acc[n][3] = fmaf(xv.z, wv2.w, acc[n][3]);
                acc[n][0] = fmaf(xv.w, wv3.x, acc[n][0]);
                acc[n][1] = fmaf(xv.w, wv3.y, acc[n][1]);
                acc[n][2] = fmaf(xv.w, wv3.z, acc[n][2]);
                acc[n][3] = fmaf(xv.w, wv3.w, acc[n][3]);
            }
        }
        __syncthreads();   // drain (prefetch had full compute phase in flight) + buffer handoff
    }
    #undef STAGE

    // epilogue: tanh, dot with W2 slice, 64-lane reduce per node
    const float4 w2v = *(const float4*)&W2[l * 4];
    const float  bb  = b2[0];
    float s_[8];
    #pragma unroll
    for (int n = 0; n < 8; ++n) {
        s_[n] = tanhf(acc[n][0]) * w2v.x + tanhf(acc[n][1]) * w2v.y
              + tanhf(acc[n][2]) * w2v.z + tanhf(acc[n][3]) * w2v.w;
    }
    #pragma unroll
    for (int off = 1; off < 64; off <<= 1)
        #pragma unroll
        for (int n = 0; n < 8; ++n)
            s_[n] += __shfl_xor(s_[n], off, 64);

    if (l == 0) {
        #pragma unroll
        for (int n = 0; n < 8; ++n)
            scores[n0 + w_ * 8 + n] = s_[n] + bb;
    }
}

// ---------------- Kernel 2: per-graph bitonic top-k (full sort of 1024) -------
__global__ __launch_bounds__(512)
void k_topk(const float* __restrict__ scores, float* __restrict__ out,
            unsigned int* __restrict__ keep_bits)
{
    __shared__ float sv[1024];
    __shared__ int   si[1024];
    const int g = blockIdx.x;
    const int t = threadIdx.x;
    sv[t]       = scores[g * NPG + t];       si[t]       = t;
    sv[t + 512] = scores[g * NPG + t + 512]; si[t + 512] = t + 512;

    for (int size = 2; size <= 1024; size <<= 1) {
        for (int stride = size >> 1; stride > 0; stride >>= 1) {
            __syncthreads();
            const int lo = ((t & ~(stride - 1)) << 1) | (t & (stride - 1));
            const int hi = lo + stride;
            const bool dirDesc = ((lo & size) == 0);
            const float va = sv[lo], vb = sv[hi];
            const int ia = si[lo], ib = si[hi];
            const bool aB = (va > vb) || (va == vb && ia < ib);
            if (aB != dirDesc) {
                sv[lo] = vb; sv[hi] = va;
                si[lo] = ib; si[hi] = ia;
            }
        }
    }
    __syncthreads();
    // rank t of this graph survives (t in [0,512))
    const int gi = g * NPG + si[t];
    out[OUT_PERM   + g * KSEL + t] = (float)gi;
    out[OUT_SCORES + g * KSEL + t] = sv[t];
    out[OUT_BATCH  + g * KSEL + t] = (float)g;
    atomicOr(&keep_bits[gi >> 5], 1u << (gi & 31));
}

// ---------------- Kernel 3: gather x_pooled ----------------
__global__ __launch_bounds__(256)
void k_gather(const float* __restrict__ x, const float* __restrict__ perm_f,
              float* __restrict__ out_x)
{
    const int row  = blockIdx.x * 4 + (threadIdx.x >> 6);
    const int lane = threadIdx.x & 63;
    const int pi = (int)perm_f[row];
    const float4* src = (const float4*)&x[(size_t)pi * CH];
    float4* dst = (float4*)&out_x[(size_t)row * CH];
    dst[lane] = src[lane];
}

// ---------------- Kernel 4: fill edge output with -1 ----------------
__global__ __launch_bounds__(256)
void k_fill(float* __restrict__ out_edge)
{
    const int i = blockIdx.x * blockDim.x + threadIdx.x;
    ((float4*)out_edge)[i] = make_float4(-1.f, -1.f, -1.f, -1.f);
}

// ---------------- Kernel 5: per-block kept-edge counts ----------------
__global__ __launch_bounds__(256)
void k_edgecount(const int* __restrict__ ei, const unsigned int* __restrict__ keep_bits,
                 int* __restrict__ counts)
{
    const int t = threadIdx.x;
    const size_t base = (size_t)blockIdx.x * 4096 + (size_t)t * 16;
    const int* rowp = ei;
    const int* colp = ei + NE;
    int rv[16], cv[16];
    #pragma unroll
    for (int q = 0; q < 4; ++q) {
        int4 r4 = *(const int4*)&rowp[base + q * 4];
        int4 c4 = *(const int4*)&colp[base + q * 4];
        rv[q*4+0]=r4.x; rv[q*4+1]=r4.y; rv[q*4+2]=r4.z; rv[q*4+3]=r4.w;
        cv[q*4+0]=c4.x; cv[q*4+1]=c4.y; cv[q*4+2]=c4.z; cv[q*4+3]=c4.w;
    }
    int cnt = 0;
    #pragma unroll
    for (int q = 0; q < 16; ++q)
        cnt += (int)((keep_bits[rv[q] >> 5] >> (rv[q] & 31)) &
                     (keep_bits[cv[q] >> 5] >> (cv[q] & 31)) & 1u);

    #pragma unroll
    for (int off = 1; off < 64; off <<= 1) cnt += __shfl_xor(cnt, off, 64);
    __shared__ int wsum[4];
    if ((t & 63) == 0) wsum[t >> 6] = cnt;
    __syncthreads();
    if (t == 0) counts[blockIdx.x] = wsum[0] + wsum[1] + wsum[2] + wsum[3];
}

// ---------------- Kernel 6: exclusive scan of 1024 block counts ----------------
__global__ __launch_bounds__(1024)
void k_scan(const int* __restrict__ counts, int* __restrict__ offsets)
{
    __shared__ int tmp[1024];
    const int t = threadIdx.x;
    const int c = counts[t];
    tmp[t] = c;
    __syncthreads();
    for (int off = 1; off < 1024; off <<= 1) {
        int v = (t >= off) ? tmp[t - off] : 0;
        __syncthreads();
        tmp[t] += v;
        __syncthreads();
    }
    offsets[t] = tmp[t] - c;
}

// ---------------- Kernel 7: stable scatter of kept edges ----------------
__global__ __launch_bounds__(256)
void k_scatter(const int* __restrict__ ei, const unsigned int* __restrict__ keep_bits,
               const int* __restrict__ offsets, float* __restrict__ out_edge)
{
    const int t = threadIdx.x;
    const size_t base = (size_t)blockIdx.x * 4096 + (size_t)t * 16;
    const int* rowp = ei;
    const int* colp = ei + NE;
    int rv[16], cv[16];
    #pragma unroll
    for (int q = 0; q < 4; ++q) {
        int4 r4 = *(const int4*)&rowp[base + q * 4];
        int4 c4 = *(const int4*)&colp[base + q * 4];
        rv[q*4+0]=r4.x; rv[q*4+1]=r4.y; rv[q*4+2]=r4.z; rv[q*4+3]=r4.w;
        cv[q*4+0]=c4.x; cv[q*4+1]=c4.y; cv[q*4+2]=c4.z; cv[q*4+3]=c4.w;
    }
    unsigned m = 0; int cnt = 0;
    #pragma unroll
    for (int q = 0; q < 16; ++q) {
        const bool kk = ((keep_bits[rv[q] >> 5] >> (rv[q] & 31)) &
                         (keep_bits[cv[q] >> 5] >> (cv[q] & 31)) & 1u) != 0u;
        m |= ((unsigned)kk) << q;
        cnt += (int)kk;
    }
    // exclusive scan over the block's 256 threads (thread chunks are contiguous
    // in edge order, so this preserves the stable original ordering)
    const int lane = t & 63, w = t >> 6;
    int incl = cnt;
    #pragma unroll
    for (int off = 1; off < 64; off <<= 1) {
        int v = __shfl_up(incl, off, 64);
        if (lane >= off) incl += v;
    }
    __shared__ int wtot[4];
    if (lane == 63) wtot[w] = incl;
    __syncthreads();
    int wbase = 0;
    for (int i = 0; i < w; ++i) wbase += wtot[i];
    int pos = offsets[blockIdx.x] + wbase + (incl - cnt);
    #pragma unroll
    for (int q = 0; q < 16; ++q) {
        if (m & (1u << q)) {
            out_edge[pos]      = (float)rv[q];
            out_edge[NE + pos] = (float)cv[q];
            ++pos;
        }
    }
}

extern "C" void kernel_launch(void* const* d_in, const int* in_sizes, int n_in,
                              void* d_out, int out_size, void* d_ws, size_t ws_size,
                              hipStream_t stream)
{
    const float* x  = (const float*)d_in[0];
    const int*   ei = (const int*)d_in[1];
    // d_in[2] (batch) is implied by the static layout; unused
    const float* W1 = (const float*)d_in[3];
    const float* b1 = (const float*)d_in[4];
    const float* W2 = (const float*)d_in[5];
    const float* b2 = (const float*)d_in[6];

    float* out = (float*)d_out;
    char*  ws  = (char*)d_ws;
    float*        scores    = (float*)(ws + WS_SCORES);
    unsigned int* keep_bits = (unsigned int*)(ws + WS_KEEP);
    int*          counts    = (int*)(ws + WS_COUNTS);
    int*          offsets   = (int*)(ws + WS_OFFSETS);

    hipMemsetAsync(keep_bits, 0, NN / 8, stream);

    k_scores<<<NN / 32, 256, 0, stream>>>(x, W1, b1, W2, b2, scores);
    k_topk<<<NG, 512, 0, stream>>>(scores, out, keep_bits);
    k_gather<<<(NG * KSEL) / 4, 256, 0, stream>>>(x, out + OUT_PERM, out + OUT_X);
    k_fill<<<(2 * NE) / (4 * 256), 256, 0, stream>>>(out + OUT_EDGE);
    k_edgecount<<<NE / 4096, 256, 0, stream>>>(ei, keep_bits, counts);
    k_scan<<<1, 1024, 0, stream>>>(counts, offsets);
    k_scatter<<<NE / 4096, 256, 0, stream>>>(ei, keep_bits, offsets, out + OUT_EDGE);
}

// Round 5
// 321.527 us; speedup vs baseline: 1.8111x; 1.0181x over previous
//
#include <hip/hip_runtime.h>
#include <hip/hip_bf16.h>

// Problem constants (static graph layout from the reference)
#define NG 128          // graphs
#define NPG 1024        // nodes per graph
#define NN (NG * NPG)   // 131072 nodes
#define NE (NN * 32)    // 4194304 edges
#define CH 256          // channels
#define KSEL 512        // top-k per graph

// Output layout (all float32, concatenated flat in return order)
#define OUT_X      0
#define OUT_EDGE   16777216   // 65536*256
#define OUT_BATCH  25165824   // + 2*4194304
#define OUT_PERM   25231360
#define OUT_SCORES 25296896
// total 25362432 floats

// Workspace layout (bytes)
#define WS_SCORES  0           // 131072 floats = 524288 B
#define WS_KEEP    524288      // bit-packed: 131072 bits = 16384 B (L1-resident)
#define WS_COUNTS  540672      // 1024 ints
#define WS_OFFSETS 544768      // 1024 ints

// ---------------- Kernel 1: scores = tanh(x@W1 + b1) @ W2 + b2 ----------------
// 32 nodes/block, 256 threads (4 waves). Wave w owns nodes 8w..8w+7; lane l owns
// output cols 4l..4l+3 -> acc[8][4] fp32 in VGPRs.
// Double-buffered global_load_lds with COMPILE-TIME buffer indices (R4's runtime
// `cur` index put LDS bases into VGPRs: 120 VGPR, 22% occupancy, regression).
// Pair-unrolled loop: {STAGE(k+1->buf1); COMPUTE(buf0); bar; STAGE(k+2->buf0);
// COMPUTE(buf1); bar}. One barrier per chunk; drain lands after ~1024 FMA-cyc.
__global__ __launch_bounds__(256, 2)
void k_scores(const float* __restrict__ x, const float* __restrict__ W1,
              const float* __restrict__ b1, const float* __restrict__ W2,
              const float* __restrict__ b2, float* __restrict__ scores)
{
    __shared__ __align__(16) float W1s[2][16][CH];  // 2 x 16 KiB
    __shared__ __align__(16) float Xs[2][32][16];   // 2 x 2 KiB

    const int tid = threadIdx.x;
    const int w_  = tid >> 6;
    const int l   = tid & 63;
    const int n0  = blockIdx.x * 32;

    const float4 b1v = *(const float4*)&b1[l * 4];
    float acc[8][4];
    #pragma unroll
    for (int n = 0; n < 8; ++n) {
        acc[n][0] = b1v.x; acc[n][1] = b1v.y; acc[n][2] = b1v.z; acc[n][3] = b1v.w;
    }

    // b_ MUST be a literal constant (compile-time LDS base).
    #define STAGE(kc_, b_)                                                          \
    do {                                                                            \
        _Pragma("unroll")                                                           \
        for (int it = 0; it < 4; ++it) {                                            \
            const float* g = W1 + (size_t)(kc_) * (16 * CH) + (w_ * 4 + it) * CH + l * 4; \
            float* lb = &W1s[b_][0][0] + (w_ * 4 + it) * CH;                        \
            __builtin_amdgcn_global_load_lds(                                       \
                (const __attribute__((address_space(1))) void*)g,                   \
                (__attribute__((address_space(3))) void*)lb, 16, 0, 0);             \
        }                                                                           \
        if (w_ < 2) {                                                               \
            const float* g = x + (size_t)(n0 + w_ * 16 + (l >> 2)) * CH + (kc_) * 16 + (l & 3) * 4; \
            float* lb = &Xs[b_][0][0] + w_ * 256;                                   \
            __builtin_amdgcn_global_load_lds(                                       \
                (const __attribute__((address_space(1))) void*)g,                   \
                (__attribute__((address_space(3))) void*)lb, 16, 0, 0);             \
        }                                                                           \
    } while (0)

    #define COMPUTE(b_)                                                             \
    do {                                                                            \
        _Pragma("unroll")                                                           \
        for (int kq = 0; kq < 4; ++kq) {                                            \
            const int k4 = kq * 4;                                                  \
            const float4 wv0 = *(const float4*)&W1s[b_][k4 + 0][l * 4];             \
            const float4 wv1 = *(const float4*)&W1s[b_][k4 + 1][l * 4];             \
            const float4 wv2 = *(const float4*)&W1s[b_][k4 + 2][l * 4];             \
            const float4 wv3 = *(const float4*)&W1s[b_][k4 + 3][l * 4];             \
            _Pragma("unroll")                                                       \
            for (int n = 0; n < 8; ++n) {                                           \
                const float4 xv = *(const float4*)&Xs[b_][w_ * 8 + n][k4];          \
                acc[n][0] = fmaf(xv.x, wv0.x, acc[n][0]);                           \
                acc[n][1] = fmaf(xv.x, wv0.y, acc[n][1]);                           \
                acc[n][2] = fmaf(xv.x, wv0.z, acc[n][2]);                           \
                acc[n][3] = fmaf(xv.x, wv0.w, acc[n][3]);                           \
                acc[n][0] = fmaf(xv.y, wv1.x, acc[n][0]);                           \
                acc[n][1] = fmaf(xv.y, wv1.y, acc[n][1]);                           \
                acc[n][2] = fmaf(xv.y, wv1.z, acc[n][2]);                           \
                acc[n][3] = fmaf(xv.y, wv1.w, acc[n][3]);                           \
                acc[n][0] = fmaf(xv.z, wv2.x, acc[n][0]);                           \
                acc[n][1] = fmaf(xv.z, wv2.y, acc[n][1]);                           \
                acc[n][2] = fmaf(xv.z, wv2.z, acc[n][2]);                           \
                acc[n][3] = fmaf(xv.z, wv2.w, acc[n][3]);                           \
                acc[n][0] = fmaf(xv.w, wv3.x, acc[n][0]);                           \
                acc[n][1] = fmaf(xv.w, wv3.y, acc[n][1]);                           \
                acc[n][2] = fmaf(xv.w, wv3.z, acc[n][2]);                           \
                acc[n][3] = fmaf(xv.w, wv3.w, acc[n][3]);                           \
            }                                                                       \
        }                                                                           \
    } while (0)

    STAGE(0, 0);
    __syncthreads();   // prologue drain

    #pragma unroll 1
    for (int p = 0; p < 8; ++p) {
        const int kc0 = p * 2;
        // half A: prefetch chunk kc0+1 into buf1, compute buf0 (chunk kc0)
        STAGE(kc0 + 1, 1);
        COMPUTE(0);
        __syncthreads();
        // half B: prefetch chunk kc0+2 into buf0, compute buf1 (chunk kc0+1)
        if (p < 7) STAGE(kc0 + 2, 0);
        COMPUTE(1);
        __syncthreads();
    }
    #undef STAGE
    #undef COMPUTE

    // epilogue: tanh, dot with W2 slice, 64-lane reduce per node
    const float4 w2v = *(const float4*)&W2[l * 4];
    const float  bb  = b2[0];
    float s_[8];
    #pragma unroll
    for (int n = 0; n < 8; ++n) {
        s_[n] = tanhf(acc[n][0]) * w2v.x + tanhf(acc[n][1]) * w2v.y
              + tanhf(acc[n][2]) * w2v.z + tanhf(acc[n][3]) * w2v.w;
    }
    #pragma unroll
    for (int off = 1; off < 64; off <<= 1)
        #pragma unroll
        for (int n = 0; n < 8; ++n)
            s_[n] += __shfl_xor(s_[n], off, 64);

    if (l == 0) {
        #pragma unroll
        for (int n = 0; n < 8; ++n)
            scores[n0 + w_ * 8 + n] = s_[n] + bb;
    }
}

// ---------------- Kernel 2: per-graph bitonic top-k (full sort of 1024) -------
__global__ __launch_bounds__(512)
void k_topk(const float* __restrict__ scores, float* __restrict__ out,
            unsigned int* __restrict__ keep_bits)
{
    __shared__ float sv[1024];
    __shared__ int   si[1024];
    const int g = blockIdx.x;
    const int t = threadIdx.x;
    sv[t]       = scores[g * NPG + t];       si[t]       = t;
    sv[t + 512] = scores[g * NPG + t + 512]; si[t + 512] = t + 512;

    for (int size = 2; size <= 1024; size <<= 1) {
        for (int stride = size >> 1; stride > 0; stride >>= 1) {
            __syncthreads();
            const int lo = ((t & ~(stride - 1)) << 1) | (t & (stride - 1));
            const int hi = lo + stride;
            const bool dirDesc = ((lo & size) == 0);
            const float va = sv[lo], vb = sv[hi];
            const int ia = si[lo], ib = si[hi];
            const bool aB = (va > vb) || (va == vb && ia < ib);
            if (aB != dirDesc) {
                sv[lo] = vb; sv[hi] = va;
                si[lo] = ib; si[hi] = ia;
            }
        }
    }
    __syncthreads();
    // rank t of this graph survives (t in [0,512))
    const int gi = g * NPG + si[t];
    out[OUT_PERM   + g * KSEL + t] = (float)gi;
    out[OUT_SCORES + g * KSEL + t] = sv[t];
    out[OUT_BATCH  + g * KSEL + t] = (float)g;
    atomicOr(&keep_bits[gi >> 5], 1u << (gi & 31));
}

// ---------------- Kernel 3: gather x_pooled ----------------
__global__ __launch_bounds__(256)
void k_gather(const float* __restrict__ x, const float* __restrict__ perm_f,
              float* __restrict__ out_x)
{
    const int row  = blockIdx.x * 4 + (threadIdx.x >> 6);
    const int lane = threadIdx.x & 63;
    const int pi = (int)perm_f[row];
    const float4* src = (const float4*)&x[(size_t)pi * CH];
    float4* dst = (float4*)&out_x[(size_t)row * CH];
    dst[lane] = src[lane];
}

// ---------------- Kernel 4: fill edge output with -1 ----------------
__global__ __launch_bounds__(256)
void k_fill(float* __restrict__ out_edge)
{
    const int i = blockIdx.x * blockDim.x + threadIdx.x;
    ((float4*)out_edge)[i] = make_float4(-1.f, -1.f, -1.f, -1.f);
}

// ---------------- Kernel 5: per-block kept-edge counts ----------------
__global__ __launch_bounds__(256)
void k_edgecount(const int* __restrict__ ei, const unsigned int* __restrict__ keep_bits,
                 int* __restrict__ counts)
{
    const int t = threadIdx.x;
    const size_t base = (size_t)blockIdx.x * 4096 + (size_t)t * 16;
    const int* rowp = ei;
    const int* colp = ei + NE;
    int rv[16], cv[16];
    #pragma unroll
    for (int q = 0; q < 4; ++q) {
        int4 r4 = *(const int4*)&rowp[base + q * 4];
        int4 c4 = *(const int4*)&colp[base + q * 4];
        rv[q*4+0]=r4.x; rv[q*4+1]=r4.y; rv[q*4+2]=r4.z; rv[q*4+3]=r4.w;
        cv[q*4+0]=c4.x; cv[q*4+1]=c4.y; cv[q*4+2]=c4.z; cv[q*4+3]=c4.w;
    }
    int cnt = 0;
    #pragma unroll
    for (int q = 0; q < 16; ++q)
        cnt += (int)((keep_bits[rv[q] >> 5] >> (rv[q] & 31)) &
                     (keep_bits[cv[q] >> 5] >> (cv[q] & 31)) & 1u);

    #pragma unroll
    for (int off = 1; off < 64; off <<= 1) cnt += __shfl_xor(cnt, off, 64);
    __shared__ int wsum[4];
    if ((t & 63) == 0) wsum[t >> 6] = cnt;
    __syncthreads();
    if (t == 0) counts[blockIdx.x] = wsum[0] + wsum[1] + wsum[2] + wsum[3];
}

// ---------------- Kernel 6: exclusive scan of 1024 block counts ----------------
__global__ __launch_bounds__(1024)
void k_scan(const int* __restrict__ counts, int* __restrict__ offsets)
{
    __shared__ int tmp[1024];
    const int t = threadIdx.x;
    const int c = counts[t];
    tmp[t] = c;
    __syncthreads();
    for (int off = 1; off < 1024; off <<= 1) {
        int v = (t >= off) ? tmp[t - off] : 0;
        __syncthreads();
        tmp[t] += v;
        __syncthreads();
    }
    offsets[t] = tmp[t] - c;
}

// ---------------- Kernel 7: stable scatter of kept edges ----------------
__global__ __launch_bounds__(256)
void k_scatter(const int* __restrict__ ei, const unsigned int* __restrict__ keep_bits,
               const int* __restrict__ offsets, float* __restrict__ out_edge)
{
    const int t = threadIdx.x;
    const size_t base = (size_t)blockIdx.x * 4096 + (size_t)t * 16;
    const int* rowp = ei;
    const int* colp = ei + NE;
    int rv[16], cv[16];
    #pragma unroll
    for (int q = 0; q < 4; ++q) {
        int4 r4 = *(const int4*)&rowp[base + q * 4];
        int4 c4 = *(const int4*)&colp[base + q * 4];
        rv[q*4+0]=r4.x; rv[q*4+1]=r4.y; rv[q*4+2]=r4.z; rv[q*4+3]=r4.w;
        cv[q*4+0]=c4.x; cv[q*4+1]=c4.y; cv[q*4+2]=c4.z; cv[q*4+3]=c4.w;
    }
    unsigned m = 0; int cnt = 0;
    #pragma unroll
    for (int q = 0; q < 16; ++q) {
        const bool kk = ((keep_bits[rv[q] >> 5] >> (rv[q] & 31)) &
                         (keep_bits[cv[q] >> 5] >> (cv[q] & 31)) & 1u) != 0u;
        m |= ((unsigned)kk) << q;
        cnt += (int)kk;
    }
    // exclusive scan over the block's 256 threads (thread chunks are contiguous
    // in edge order, so this preserves the stable original ordering)
    const int lane = t & 63, w = t >> 6;
    int incl = cnt;
    #pragma unroll
    for (int off = 1; off < 64; off <<= 1) {
        int v = __shfl_up(incl, off, 64);
        if (lane >= off) incl += v;
    }
    __shared__ int wtot[4];
    if (lane == 63) wtot[w] = incl;
    __syncthreads();
    int wbase = 0;
    for (int i = 0; i < w; ++i) wbase += wtot[i];
    int pos = offsets[blockIdx.x] + wbase + (incl - cnt);
    #pragma unroll
    for (int q = 0; q < 16; ++q) {
        if (m & (1u << q)) {
            out_edge[pos]      = (float)rv[q];
            out_edge[NE + pos] = (float)cv[q];
            ++pos;
        }
    }
}

extern "C" void kernel_launch(void* const* d_in, const int* in_sizes, int n_in,
                              void* d_out, int out_size, void* d_ws, size_t ws_size,
                              hipStream_t stream)
{
    const float* x  = (const float*)d_in[0];
    const int*   ei = (const int*)d_in[1];
    // d_in[2] (batch) is implied by the static layout; unused
    const float* W1 = (const float*)d_in[3];
    const float* b1 = (const float*)d_in[4];
    const float* W2 = (const float*)d_in[5];
    const float* b2 = (const float*)d_in[6];

    float* out = (float*)d_out;
    char*  ws  = (char*)d_ws;
    float*        scores    = (float*)(ws + WS_SCORES);
    unsigned int* keep_bits = (unsigned int*)(ws + WS_KEEP);
    int*          counts    = (int*)(ws + WS_COUNTS);
    int*          offsets   = (int*)(ws + WS_OFFSETS);

    hipMemsetAsync(keep_bits, 0, NN / 8, stream);

    k_scores<<<NN / 32, 256, 0, stream>>>(x, W1, b1, W2, b2, scores);
    k_topk<<<NG, 512, 0, stream>>>(scores, out, keep_bits);
    k_gather<<<(NG * KSEL) / 4, 256, 0, stream>>>(x, out + OUT_PERM, out + OUT_X);
    k_fill<<<(2 * NE) / (4 * 256), 256, 0, stream>>>(out + OUT_EDGE);
    k_edgecount<<<NE / 4096, 256, 0, stream>>>(ei, keep_bits, counts);
    k_scan<<<1, 1024, 0, stream>>>(counts, offsets);
    k_scatter<<<NE / 4096, 256, 0, stream>>>(ei, keep_bits, offsets, out + OUT_EDGE);
}